// Round 16
// baseline (77.095 us; speedup 1.0000x reference)
//
#include <hip/hip_runtime.h>

#define C_IN 64
#define C_OUT 8
#define IMG 128
#define HW (IMG * IMG)
#define BATCH 32
#define K_STEPS 8

#define FEAT_BYTES ((size_t)BATCH * HW * C_OUT * 4)   // 16,777,216
#define BLK_PER_B 16
#define NROUNDS (K_STEPS - 1)
#define NFLAGS (NROUNDS * BATCH * BLK_PER_B)          // 3584 u64
#define NT 1024
#define NW (NT / 64)                                  // 16 waves
#define CHUNK (HW / BLK_PER_B)                        // 1024 px per block

// ---------------------------------------------------------------------------
// Kernel A (validated): 1x1 conv + gate + bias + coords, step-0 rand-argmax
// per block -> seed0[], flag zeroing by block 0.
// ---------------------------------------------------------------------------
__global__ __launch_bounds__(256) void semiconv_kernel(
    const float* __restrict__ x,      // [B][C_IN][HW]
    const float* __restrict__ w,      // [C_OUT][C_IN]
    const float* __restrict__ bias,   // [C_OUT]
    const float* __restrict__ gate_p, // scalar
    const float* __restrict__ rand_pixel, // [B][HW]
    float* __restrict__ feat,         // [B][HW][C_OUT]
    unsigned long long* __restrict__ flags,
    unsigned long long* __restrict__ seed0)
{
    __shared__ float sw[C_OUT * C_IN];
    __shared__ float spv[4];
    __shared__ int   spi[4];
    const int tid = threadIdx.x;
    if (blockIdx.x == 0) {
        for (int k = tid; k < NFLAGS; k += 256) flags[k] = 0ULL;
    }
    for (int i = tid; i < C_OUT * C_IN; i += 256) sw[i] = w[i];

    const int b     = blockIdx.x >> 4;
    const int blk16 = blockIdx.x & 15;
    const int p4    = ((blk16 * 256) + tid) * 4;
    const int lane  = tid & 63;
    const int wid   = tid >> 6;

    {
        const float4 rv = *(const float4*)(rand_pixel + (size_t)b * HW + p4);
        float bv = rv.x; int bi = p4;
        if (rv.y > bv) { bv = rv.y; bi = p4 + 1; }   // ascending, strict >
        if (rv.z > bv) { bv = rv.z; bi = p4 + 2; }
        if (rv.w > bv) { bv = rv.w; bi = p4 + 3; }
        #pragma unroll
        for (int off = 1; off < 64; off <<= 1) {
            const float ov = __shfl_xor(bv, off);
            const int   oi = __shfl_xor(bi, off);
            if (ov > bv || (ov == bv && oi < bi)) { bv = ov; bi = oi; }
        }
        if (lane == 0) { spv[wid] = bv; spi[wid] = bi; }
    }
    __syncthreads();   // covers sw staging AND spv/spi
    if (tid == 0) {
        float v = spv[0]; int ix = spi[0];
        #pragma unroll
        for (int wv2 = 1; wv2 < 4; ++wv2) {
            if (spv[wv2] > v || (spv[wv2] == v && spi[wv2] < ix)) { v = spv[wv2]; ix = spi[wv2]; }
        }
        seed0[(b << 4) | blk16] =
            ((unsigned long long)__float_as_uint(v) << 32) |
            (unsigned long long)(unsigned int)ix;
    }

    const float gate = *gate_p;
    const float* xb = x + (long long)b * C_IN * HW + p4;

    float acc[C_OUT][4];
    #pragma unroll
    for (int o = 0; o < C_OUT; ++o) {
        const float bv = bias[o];
        #pragma unroll
        for (int j = 0; j < 4; ++j) acc[o][j] = bv;
    }

    for (int c = 0; c < C_IN; ++c) {
        const float4 xv = *(const float4*)(xb + c * HW);
        const float xs[4] = {xv.x, xv.y, xv.z, xv.w};
        #pragma unroll
        for (int o = 0; o < C_OUT; ++o) {
            const float wv = sw[o * C_IN + c];
            #pragma unroll
            for (int j = 0; j < 4; ++j) acc[o][j] = fmaf(wv, xs[j], acc[o][j]);
        }
    }

    const int row  = p4 / IMG;
    const int col0 = p4 % IMG;
    const float step = 2.0f / (IMG - 1);
    const float g1 = -1.0f + step * (float)row;

    float* dst = feat + ((long long)b * HW + p4) * C_OUT;
    #pragma unroll
    for (int j = 0; j < 4; ++j) {
        float o0 = gate * acc[0][j];
        float o1 = gate * acc[1][j];
        float o2 = gate * acc[2][j];
        float o3 = gate * acc[3][j];
        float o4 = gate * acc[4][j];
        float o5 = gate * acc[5][j];
        float o6 = gate * acc[6][j] + g1;
        float o7 = gate * acc[7][j] + (-1.0f + step * (float)(col0 + j));
        *(float4*)(dst + j * C_OUT)     = make_float4(o0, o1, o2, o3);
        *(float4*)(dst + j * C_OUT + 4) = make_float4(o4, o5, o6, o7);
    }
}

// ---------------------------------------------------------------------------
// Kernel B (r16): r14's shape (16 blocks/batch, grid 512, 1 px/thread,
// __launch_bounds__(1024,8) => VGPR<=64 => 2 blocks/CU, all 512 resident)
// with ONE change: CROSS-BATCH CO-RESIDENCY REMAP. Co-resident pair
// (i, i+256) now serves batches b and (b+8)&31 (r14 paired the SAME batch).
// While one block's waves park at the barrier during its wave0's global
// publish/poll RTT, the other batch's block issues compute. The remap
// preserves b%8 == blockIdx%8, so each batch's flags stay XCD-local.
// Sync: EXACT r7 protocol, 16 flag words/batch/step. Step-0 seed from
// seed0[]. argmax / alpha / log1pf math bitwise identical to the validated
// r5-r15 path ((max,min-idx) order is reduction-topology independent).
// ---------------------------------------------------------------------------
__global__ __launch_bounds__(NT, 8) void stick_kernel(
    const float* __restrict__ feat,        // [B][HW][C_OUT]
    const float* __restrict__ rand_pixel,  // [B][HW]
    const float* __restrict__ log_sigma_p, // scalar
    float* __restrict__ masks,             // [B][K][HW]
    float* __restrict__ scopes,            // [B][K][HW]
    unsigned long long* __restrict__ flags,// [7][B][BLK_PER_B]
    const unsigned long long* __restrict__ seed0) // [B][16]
{
    // cross-batch co-residency remap (see header comment)
    const int i    = blockIdx.x;
    const int half = i >> 8;               // 0: lower 256 blocks, 1: upper
    const int j    = i & 255;
    const int b    = ((j & 31) + (half << 3)) & 31;  // +8 for upper half
    const int blk  = (j >> 5) + (half << 3);         // 0..15
    const int tid  = threadIdx.x;
    const int lane = tid & 63;
    const int wid  = tid >> 6;             // 0..15

    const float inv_sigma = expf(-(*log_sigma_p));

    const float* fb = feat + (size_t)b * HW * C_OUT;
    const float* rb = rand_pixel + (size_t)b * HW;
    float* mb = masks  + (size_t)b * (K_STEPS * HW);
    float* sb = scopes + (size_t)b * (K_STEPS * HW);

    const int p0 = blk * CHUNK + tid;      // ONE pixel per thread

    const float4 fa = *(const float4*)(fb + (size_t)p0 * C_OUT);
    const float4 fc = *(const float4*)(fb + (size_t)p0 * C_OUT + 4);

    const float rr = rb[p0];
    float ls0 = 0.0f;
    __builtin_nontemporal_store(0.0f, sb + p0);   // log_scopes[:,0] = 0

    __shared__ float swv[2][NW];
    __shared__ int   swi[2][NW];
    __shared__ int   sSeed[2];

    for (int s = 0; s < NROUNDS; ++s) {
        const int par = s & 1;
        int seedIdx;

        if (s == 0) {
            // seed precomputed by semiconv: reduce the 16 slots, no sync
            float gv = -1.0f; int gi = 0x7fffffff;
            if (lane < 16) {
                const unsigned long long got = seed0[(b << 4) | lane];
                gv = __uint_as_float((unsigned int)(got >> 32));
                gi = (int)(unsigned int)(got & 0xffffffffULL);
            }
            #pragma unroll
            for (int off = 1; off < 16; off <<= 1) {
                const float ov = __shfl_xor(gv, off);
                const int   oi = __shfl_xor(gi, off);
                if (ov > gv || (ov == gv && oi < gi)) { gv = ov; gi = oi; }
            }
            seedIdx = __shfl(gi, 0);
        } else {
            const int recbase = (s * BATCH + b) * BLK_PER_B;

            // ---- per-thread value, 64-lane butterfly (max, tie->min idx) ----
            float bv = rr * expf(ls0);
            int   bi = p0;
            #pragma unroll
            for (int off = 1; off < 64; off <<= 1) {
                const float ov = __shfl_xor(bv, off);
                const int   oi = __shfl_xor(bi, off);
                if (ov > bv || (ov == bv && oi < bi)) { bv = ov; bi = oi; }
            }
            if (lane == 0) { swv[par][wid] = bv; swi[par][wid] = bi; }
            __syncthreads();               // barrier 1

            // ---- wave 0: reduce 16 partials, publish, poll 16 peers ----
            if (wid == 0) {
                float v = (lane < NW) ? swv[par][lane] : -1.0f;
                int   ix = (lane < NW) ? swi[par][lane] : 0x7fffffff;
                #pragma unroll
                for (int off = 1; off < 16; off <<= 1) {
                    const float ov = __shfl_xor(v, off);
                    const int   oi = __shfl_xor(ix, off);
                    if (ov > v || (ov == v && oi < ix)) { v = ov; ix = oi; }
                }
                if (lane == 0) {
                    const unsigned long long pk =
                        ((unsigned long long)__float_as_uint(v) << 32) |
                        (unsigned long long)(unsigned int)(ix + 1);
                    __hip_atomic_store(&flags[recbase + blk], pk,
                                       __ATOMIC_RELAXED, __HIP_MEMORY_SCOPE_AGENT);
                }
                float gv = -1.0f; int gi = 0x7fffffff;
                if (lane < BLK_PER_B) {
                    unsigned long long got;
                    do {
                        got = __hip_atomic_load(&flags[recbase + lane],
                                                __ATOMIC_RELAXED,
                                                __HIP_MEMORY_SCOPE_AGENT);
                    } while (got == 0ULL);
                    gv = __uint_as_float((unsigned int)(got >> 32));
                    gi = (int)(unsigned int)(got & 0xffffffffULL) - 1;
                }
                #pragma unroll
                for (int off = 1; off < 16; off <<= 1) {
                    const float ov = __shfl_xor(gv, off);
                    const int   oi = __shfl_xor(gi, off);
                    if (ov > gv || (ov == gv && oi < gi)) { gv = ov; gi = oi; }
                }
                if (lane == 0) sSeed[par] = gi;
            }
            __syncthreads();               // barrier 2
            seedIdx = sSeed[par];
        }

        // seed features (uniform address -> broadcast load, L2/L3-hot)
        const float4 s0 = *(const float4*)(fb + (size_t)seedIdx * C_OUT);
        const float4 s1 = *(const float4*)(fb + (size_t)seedIdx * C_OUT + 4);

        // ---- distance, alpha, mask/scope update (validated math) ----
        float sq0 = 0.0f, d;
        d = fa.x - s0.x; sq0 += d * d;
        d = fa.y - s0.y; sq0 += d * d;
        d = fa.z - s0.z; sq0 += d * d;
        d = fa.w - s0.w; sq0 += d * d;
        d = fc.x - s1.x; sq0 += d * d;
        d = fc.y - s1.y; sq0 += d * d;
        d = fc.z - s1.z; sq0 += d * d;
        d = fc.w - s1.w; sq0 += d * d;

        const float t = sq0 * inv_sigma;
        float alpha = expf(-t);
        float log_a;
        if (alpha >= 0.99f)      { alpha = 0.99f; log_a = -0.010050336f; } // ln(0.99)
        else if (alpha <= 0.01f) { alpha = 0.01f; log_a = -4.6051702f;  }  // ln(0.01)
        else                     { log_a = -t; }
        const float m0 = ls0 + log_a;
        ls0 += log1pf(-alpha);

        __builtin_nontemporal_store(m0,  mb + s * HW + p0);
        __builtin_nontemporal_store(ls0, sb + (s + 1) * HW + p0);
    }

    __builtin_nontemporal_store(ls0, mb + (K_STEPS - 1) * HW + p0); // last mask
}

extern "C" void kernel_launch(void* const* d_in, const int* in_sizes, int n_in,
                              void* d_out, int out_size, void* d_ws, size_t ws_size,
                              hipStream_t stream) {
    const float* x          = (const float*)d_in[0];  // [32,64,128,128]
    const float* rand_pixel = (const float*)d_in[1];  // [32,1,128,128]
    const float* conv_w     = (const float*)d_in[2];  // [8,64]
    const float* conv_b     = (const float*)d_in[3];  // [8]
    const float* gate       = (const float*)d_in[4];  // scalar
    const float* log_sigma  = (const float*)d_in[5];  // scalar

    float* masks  = (float*)d_out;                          // [32,8,128,128]
    float* scopes = masks + (long long)BATCH * K_STEPS * HW;

    float* feat = (float*)d_ws;  // 16.8 MB
    unsigned long long* flags =
        (unsigned long long*)((char*)d_ws + FEAT_BYTES);               // 28 KB
    unsigned long long* seed0 = flags + NFLAGS;                        // 4 KB

    semiconv_kernel<<<(BATCH * HW) / (256 * 4), 256, 0, stream>>>(
        x, conv_w, conv_b, gate, rand_pixel, feat, flags, seed0);

    stick_kernel<<<BATCH * BLK_PER_B, NT, 0, stream>>>(
        feat, rand_pixel, log_sigma, masks, scopes, flags, seed0);
}

// Round 17
// 74.475 us; speedup vs baseline: 1.0352x; 1.0352x over previous
//
#include <hip/hip_runtime.h>

#define C_IN 64
#define C_OUT 8
#define IMG 128
#define HW (IMG * IMG)
#define BATCH 32
#define K_STEPS 8

#define FEAT_BYTES ((size_t)BATCH * HW * C_OUT * 4)   // 16,777,216
#define BLK_PER_B 8
#define NROUNDS (K_STEPS - 1)
#define NFLAGS (NROUNDS * BATCH * BLK_PER_B)          // 1792 u64

union F2U { float2 f2; unsigned long long u; };
__device__ __forceinline__ void nt_store2(float* p, float a, float b2) {
    F2U v; v.f2 = make_float2(a, b2);
    __builtin_nontemporal_store(v.u, (unsigned long long*)p);
}

// ---------------------------------------------------------------------------
// Kernel A (r10, validated): 1x1 conv + gate + bias + coords; step-0
// rand-argmax per block -> seed0[]; block 0 zeroes the flags.
// ---------------------------------------------------------------------------
__global__ __launch_bounds__(256) void semiconv_kernel(
    const float* __restrict__ x,      // [B][C_IN][HW]
    const float* __restrict__ w,      // [C_OUT][C_IN]
    const float* __restrict__ bias,   // [C_OUT]
    const float* __restrict__ gate_p, // scalar
    const float* __restrict__ rand_pixel, // [B][HW]
    float* __restrict__ feat,         // [B][HW][C_OUT]
    unsigned long long* __restrict__ flags,
    unsigned long long* __restrict__ seed0)
{
    __shared__ float sw[C_OUT * C_IN];
    __shared__ float spv[4];
    __shared__ int   spi[4];
    const int tid = threadIdx.x;
    if (blockIdx.x == 0) {
        for (int k = tid; k < NFLAGS; k += 256) flags[k] = 0ULL;
    }
    for (int i = tid; i < C_OUT * C_IN; i += 256) sw[i] = w[i];

    const int b     = blockIdx.x >> 4;
    const int blk16 = blockIdx.x & 15;
    const int p4    = ((blk16 * 256) + tid) * 4;
    const int lane  = tid & 63;
    const int wid   = tid >> 6;

    {
        const float4 rv = *(const float4*)(rand_pixel + (size_t)b * HW + p4);
        float bv = rv.x; int bi = p4;
        if (rv.y > bv) { bv = rv.y; bi = p4 + 1; }   // ascending, strict >
        if (rv.z > bv) { bv = rv.z; bi = p4 + 2; }
        if (rv.w > bv) { bv = rv.w; bi = p4 + 3; }
        #pragma unroll
        for (int off = 1; off < 64; off <<= 1) {
            const float ov = __shfl_xor(bv, off);
            const int   oi = __shfl_xor(bi, off);
            if (ov > bv || (ov == bv && oi < bi)) { bv = ov; bi = oi; }
        }
        if (lane == 0) { spv[wid] = bv; spi[wid] = bi; }
    }
    __syncthreads();   // covers sw staging AND spv/spi
    if (tid == 0) {
        float v = spv[0]; int ix = spi[0];
        #pragma unroll
        for (int wv2 = 1; wv2 < 4; ++wv2) {
            if (spv[wv2] > v || (spv[wv2] == v && spi[wv2] < ix)) { v = spv[wv2]; ix = spi[wv2]; }
        }
        seed0[(b << 4) | blk16] =
            ((unsigned long long)__float_as_uint(v) << 32) |
            (unsigned long long)(unsigned int)ix;
    }

    const float gate = *gate_p;
    const float* xb = x + (long long)b * C_IN * HW + p4;

    float acc[C_OUT][4];
    #pragma unroll
    for (int o = 0; o < C_OUT; ++o) {
        const float bv = bias[o];
        #pragma unroll
        for (int j = 0; j < 4; ++j) acc[o][j] = bv;
    }

    for (int c = 0; c < C_IN; ++c) {
        const float4 xv = *(const float4*)(xb + c * HW);
        const float xs[4] = {xv.x, xv.y, xv.z, xv.w};
        #pragma unroll
        for (int o = 0; o < C_OUT; ++o) {
            const float wv = sw[o * C_IN + c];
            #pragma unroll
            for (int j = 0; j < 4; ++j) acc[o][j] = fmaf(wv, xs[j], acc[o][j]);
        }
    }

    const int row  = p4 / IMG;
    const int col0 = p4 % IMG;
    const float step = 2.0f / (IMG - 1);
    const float g1 = -1.0f + step * (float)row;

    float* dst = feat + ((long long)b * HW + p4) * C_OUT;
    #pragma unroll
    for (int j = 0; j < 4; ++j) {
        float o0 = gate * acc[0][j];
        float o1 = gate * acc[1][j];
        float o2 = gate * acc[2][j];
        float o3 = gate * acc[3][j];
        float o4 = gate * acc[4][j];
        float o5 = gate * acc[5][j];
        float o6 = gate * acc[6][j] + g1;
        float o7 = gate * acc[7][j] + (-1.0f + step * (float)(col0 + j));
        *(float4*)(dst + j * C_OUT)     = make_float4(o0, o1, o2, o3);
        *(float4*)(dst + j * C_OUT + 4) = make_float4(o4, o5, o6, o7);
    }
}

// ---------------------------------------------------------------------------
// Kernel B (r17): EXACT r10 structure with ONE transport change: wave0
// prefetches the winning seed's 8-float feature into LDS during its
// poll phase (while the other 15 waves are parked at barrier 2). After
// wake-up, all waves read the feature from LDS (~120cy) instead of each
// issuing a dependent global uniform load (~300-900cy L2/L3 hop). The
// sSeed index broadcast is deleted (compute only needs the feature).
// Float values bit-identical to the validated r5-r16 path; steps >= 1 only.
// ---------------------------------------------------------------------------
#define NT 1024
#define CHUNK (HW / BLK_PER_B)   // 2048

__global__ __launch_bounds__(NT) void stick_kernel(
    const float* __restrict__ feat,        // [B][HW][C_OUT]
    const float* __restrict__ rand_pixel,  // [B][HW]
    const float* __restrict__ log_sigma_p, // scalar
    float* __restrict__ masks,             // [B][K][HW]
    float* __restrict__ scopes,            // [B][K][HW]
    unsigned long long* __restrict__ flags,// [7][B][BLK_PER_B]
    const unsigned long long* __restrict__ seed0) // [B][16]
{
    // batch b's 8 blocks share blockIdx%8 -> same XCD (L2-local flags).
    const int b    = blockIdx.x & 31;
    const int blk  = blockIdx.x >> 5;
    const int tid  = threadIdx.x;
    const int lane = tid & 63;
    const int wid  = tid >> 6;             // 0..15

    const float inv_sigma = expf(-(*log_sigma_p));

    const float* fb = feat + (size_t)b * HW * C_OUT;
    const float* rb = rand_pixel + (size_t)b * HW;
    float* mb = masks  + (size_t)b * (K_STEPS * HW);
    float* sb = scopes + (size_t)b * (K_STEPS * HW);

    const int p0 = blk * CHUNK + 2 * tid;  // adjacent pixels p0, p0+1

    const float4 f0a = *(const float4*)(fb + (size_t)p0 * C_OUT);
    const float4 f0b = *(const float4*)(fb + (size_t)p0 * C_OUT + 4);
    const float4 f1a = *(const float4*)(fb + (size_t)p0 * C_OUT + 8);
    const float4 f1b = *(const float4*)(fb + (size_t)p0 * C_OUT + 12);

    const float2 rr = *(const float2*)(rb + p0);
    float ls0 = 0.0f, ls1 = 0.0f;
    nt_store2(sb + p0, 0.0f, 0.0f);        // log_scopes[:,0] = 0

    __shared__ float swv[2][16];
    __shared__ int   swi[2][16];
    __shared__ __align__(16) float sSeedF[2][C_OUT];

    for (int s = 0; s < NROUNDS; ++s) {
        const int par = s & 1;
        float4 s0, s1;

        if (s == 0) {
            // seed precomputed by semiconv: every wave reduces the 16 slots
            float gv = -1.0f; int gi = 0x7fffffff;
            if (lane < 16) {
                const unsigned long long got = seed0[(b << 4) | lane];
                gv = __uint_as_float((unsigned int)(got >> 32));
                gi = (int)(unsigned int)(got & 0xffffffffULL);
            }
            #pragma unroll
            for (int off = 1; off < 16; off <<= 1) {
                const float ov = __shfl_xor(gv, off);
                const int   oi = __shfl_xor(gi, off);
                if (ov > gv || (ov == gv && oi < gi)) { gv = ov; gi = oi; }
            }
            const int seedIdx = __shfl(gi, 0);
            s0 = *(const float4*)(fb + (size_t)seedIdx * C_OUT);
            s1 = *(const float4*)(fb + (size_t)seedIdx * C_OUT + 4);
        } else {
            const int recbase = (s * BATCH + b) * BLK_PER_B;

            // ---- per-thread argmax of rand * exp(log_scope) ----
            float bv; int bi;
            {
                const float v0 = rr.x * expf(ls0);
                const float v1 = rr.y * expf(ls1);
                bv = v0; bi = p0;
                if (v1 > bv) { bv = v1; bi = p0 + 1; }  // strict > keeps lower idx
            }
            #pragma unroll
            for (int off = 1; off < 64; off <<= 1) {
                const float ov = __shfl_xor(bv, off);
                const int   oi = __shfl_xor(bi, off);
                if (ov > bv || (ov == bv && oi < bi)) { bv = ov; bi = oi; }
            }
            if (lane == 0) { swv[par][wid] = bv; swi[par][wid] = bi; }
            __syncthreads();               // barrier 1

            // ---- wave 0: reduce, publish, poll, reduce, PREFETCH SEED ----
            if (wid == 0) {
                float v = (lane < 16) ? swv[par][lane] : -1.0f;
                int   ix = (lane < 16) ? swi[par][lane] : 0x7fffffff;
                #pragma unroll
                for (int off = 1; off < 16; off <<= 1) {
                    const float ov = __shfl_xor(v, off);
                    const int   oi = __shfl_xor(ix, off);
                    if (ov > v || (ov == v && oi < ix)) { v = ov; ix = oi; }
                }
                if (lane == 0) {
                    const unsigned long long pk =
                        ((unsigned long long)__float_as_uint(v) << 32) |
                        (unsigned long long)(unsigned int)(ix + 1);
                    __hip_atomic_store(&flags[recbase + blk], pk,
                                       __ATOMIC_RELAXED, __HIP_MEMORY_SCOPE_AGENT);
                }
                float gv = -1.0f; int gi = 0x7fffffff;
                if (lane < BLK_PER_B) {
                    unsigned long long got;
                    do {
                        got = __hip_atomic_load(&flags[recbase + lane],
                                                __ATOMIC_RELAXED,
                                                __HIP_MEMORY_SCOPE_AGENT);
                    } while (got == 0ULL);
                    gv = __uint_as_float((unsigned int)(got >> 32));
                    gi = (int)(unsigned int)(got & 0xffffffffULL) - 1;
                }
                #pragma unroll
                for (int off = 1; off < 8; off <<= 1) {
                    const float ov = __shfl_xor(gv, off);
                    const int   oi = __shfl_xor(gi, off);
                    if (ov > gv || (ov == gv && oi < gi)) { gv = ov; gi = oi; }
                }
                // all lanes of wave0 hold the winner; lanes 0..7 fetch the
                // feature into LDS while the other waves are parked.
                if (lane < C_OUT) {
                    sSeedF[par][lane] = fb[(size_t)gi * C_OUT + lane];
                }
            }
            __syncthreads();               // barrier 2
            s0 = *(const float4*)&sSeedF[par][0];
            s1 = *(const float4*)&sSeedF[par][4];
        }

        // ---- distances, alpha, mask/scope update (validated math) ----
        float sq0 = 0.0f, sq1 = 0.0f, d;
        d = f0a.x - s0.x; sq0 += d * d;
        d = f0a.y - s0.y; sq0 += d * d;
        d = f0a.z - s0.z; sq0 += d * d;
        d = f0a.w - s0.w; sq0 += d * d;
        d = f0b.x - s1.x; sq0 += d * d;
        d = f0b.y - s1.y; sq0 += d * d;
        d = f0b.z - s1.z; sq0 += d * d;
        d = f0b.w - s1.w; sq0 += d * d;
        d = f1a.x - s0.x; sq1 += d * d;
        d = f1a.y - s0.y; sq1 += d * d;
        d = f1a.z - s0.z; sq1 += d * d;
        d = f1a.w - s0.w; sq1 += d * d;
        d = f1b.x - s1.x; sq1 += d * d;
        d = f1b.y - s1.y; sq1 += d * d;
        d = f1b.z - s1.z; sq1 += d * d;
        d = f1b.w - s1.w; sq1 += d * d;

        float m0, m1;
        {
            const float t = sq0 * inv_sigma;
            float alpha = expf(-t);
            float log_a;
            if (alpha >= 0.99f)      { alpha = 0.99f; log_a = -0.010050336f; } // ln(0.99)
            else if (alpha <= 0.01f) { alpha = 0.01f; log_a = -4.6051702f;  }  // ln(0.01)
            else                     { log_a = -t; }
            m0 = ls0 + log_a;
            ls0 += log1pf(-alpha);
        }
        {
            const float t = sq1 * inv_sigma;
            float alpha = expf(-t);
            float log_a;
            if (alpha >= 0.99f)      { alpha = 0.99f; log_a = -0.010050336f; }
            else if (alpha <= 0.01f) { alpha = 0.01f; log_a = -4.6051702f;  }
            else                     { log_a = -t; }
            m1 = ls1 + log_a;
            ls1 += log1pf(-alpha);
        }
        nt_store2(mb + s * HW + p0, m0, m1);
        nt_store2(sb + (s + 1) * HW + p0, ls0, ls1);
    }

    nt_store2(mb + (K_STEPS - 1) * HW + p0, ls0, ls1);  // last mask = final scope
}

extern "C" void kernel_launch(void* const* d_in, const int* in_sizes, int n_in,
                              void* d_out, int out_size, void* d_ws, size_t ws_size,
                              hipStream_t stream) {
    const float* x          = (const float*)d_in[0];  // [32,64,128,128]
    const float* rand_pixel = (const float*)d_in[1];  // [32,1,128,128]
    const float* conv_w     = (const float*)d_in[2];  // [8,64]
    const float* conv_b     = (const float*)d_in[3];  // [8]
    const float* gate       = (const float*)d_in[4];  // scalar
    const float* log_sigma  = (const float*)d_in[5];  // scalar

    float* masks  = (float*)d_out;                          // [32,8,128,128]
    float* scopes = masks + (long long)BATCH * K_STEPS * HW;

    float* feat = (float*)d_ws;  // 16.8 MB
    unsigned long long* flags =
        (unsigned long long*)((char*)d_ws + FEAT_BYTES);               // 14 KB
    unsigned long long* seed0 = flags + NFLAGS;                        // 4 KB

    semiconv_kernel<<<(BATCH * HW) / (256 * 4), 256, 0, stream>>>(
        x, conv_w, conv_b, gate, rand_pixel, feat, flags, seed0);

    stick_kernel<<<BATCH * BLK_PER_B, NT, 0, stream>>>(
        feat, rand_pixel, log_sigma, masks, scopes, flags, seed0);
}

// Round 18
// 63.884 us; speedup vs baseline: 1.2068x; 1.1658x over previous
//
#include <hip/hip_runtime.h>

#define C_IN 64
#define C_OUT 8
#define IMG 128
#define HW (IMG * IMG)
#define BATCH 32
#define K_STEPS 8

#define FEAT_BYTES ((size_t)BATCH * HW * C_OUT * 4)   // 16,777,216
#define BLK_PER_B 8
#define NROUNDS (K_STEPS - 1)
#define NFLAGS (NROUNDS * BATCH * BLK_PER_B)          // 1792 u64

union F2U { float2 f2; unsigned long long u; };
__device__ __forceinline__ void nt_store2(float* p, float a, float b2) {
    F2U v; v.f2 = make_float2(a, b2);
    __builtin_nontemporal_store(v.u, (unsigned long long*)p);
}

// ---------------------------------------------------------------------------
// Kernel A (r10, validated): 1x1 conv + gate + bias + coords; step-0
// rand-argmax per block -> seed0[]; block 0 zeroes the flags.
// ---------------------------------------------------------------------------
__global__ __launch_bounds__(256) void semiconv_kernel(
    const float* __restrict__ x,      // [B][C_IN][HW]
    const float* __restrict__ w,      // [C_OUT][C_IN]
    const float* __restrict__ bias,   // [C_OUT]
    const float* __restrict__ gate_p, // scalar
    const float* __restrict__ rand_pixel, // [B][HW]
    float* __restrict__ feat,         // [B][HW][C_OUT]
    unsigned long long* __restrict__ flags,
    unsigned long long* __restrict__ seed0)
{
    __shared__ float sw[C_OUT * C_IN];
    __shared__ float spv[4];
    __shared__ int   spi[4];
    const int tid = threadIdx.x;
    if (blockIdx.x == 0) {
        for (int k = tid; k < NFLAGS; k += 256) flags[k] = 0ULL;
    }
    for (int i = tid; i < C_OUT * C_IN; i += 256) sw[i] = w[i];

    const int b     = blockIdx.x >> 4;
    const int blk16 = blockIdx.x & 15;
    const int p4    = ((blk16 * 256) + tid) * 4;
    const int lane  = tid & 63;
    const int wid   = tid >> 6;

    {
        const float4 rv = *(const float4*)(rand_pixel + (size_t)b * HW + p4);
        float bv = rv.x; int bi = p4;
        if (rv.y > bv) { bv = rv.y; bi = p4 + 1; }   // ascending, strict >
        if (rv.z > bv) { bv = rv.z; bi = p4 + 2; }
        if (rv.w > bv) { bv = rv.w; bi = p4 + 3; }
        #pragma unroll
        for (int off = 1; off < 64; off <<= 1) {
            const float ov = __shfl_xor(bv, off);
            const int   oi = __shfl_xor(bi, off);
            if (ov > bv || (ov == bv && oi < bi)) { bv = ov; bi = oi; }
        }
        if (lane == 0) { spv[wid] = bv; spi[wid] = bi; }
    }
    __syncthreads();   // covers sw staging AND spv/spi
    if (tid == 0) {
        float v = spv[0]; int ix = spi[0];
        #pragma unroll
        for (int wv2 = 1; wv2 < 4; ++wv2) {
            if (spv[wv2] > v || (spv[wv2] == v && spi[wv2] < ix)) { v = spv[wv2]; ix = spi[wv2]; }
        }
        seed0[(b << 4) | blk16] =
            ((unsigned long long)__float_as_uint(v) << 32) |
            (unsigned long long)(unsigned int)ix;
    }

    const float gate = *gate_p;
    const float* xb = x + (long long)b * C_IN * HW + p4;

    float acc[C_OUT][4];
    #pragma unroll
    for (int o = 0; o < C_OUT; ++o) {
        const float bv = bias[o];
        #pragma unroll
        for (int j = 0; j < 4; ++j) acc[o][j] = bv;
    }

    for (int c = 0; c < C_IN; ++c) {
        const float4 xv = *(const float4*)(xb + c * HW);
        const float xs[4] = {xv.x, xv.y, xv.z, xv.w};
        #pragma unroll
        for (int o = 0; o < C_OUT; ++o) {
            const float wv = sw[o * C_IN + c];
            #pragma unroll
            for (int j = 0; j < 4; ++j) acc[o][j] = fmaf(wv, xs[j], acc[o][j]);
        }
    }

    const int row  = p4 / IMG;
    const int col0 = p4 % IMG;
    const float step = 2.0f / (IMG - 1);
    const float g1 = -1.0f + step * (float)row;

    float* dst = feat + ((long long)b * HW + p4) * C_OUT;
    #pragma unroll
    for (int j = 0; j < 4; ++j) {
        float o0 = gate * acc[0][j];
        float o1 = gate * acc[1][j];
        float o2 = gate * acc[2][j];
        float o3 = gate * acc[3][j];
        float o4 = gate * acc[4][j];
        float o5 = gate * acc[5][j];
        float o6 = gate * acc[6][j] + g1;
        float o7 = gate * acc[7][j] + (-1.0f + step * (float)(col0 + j));
        *(float4*)(dst + j * C_OUT)     = make_float4(o0, o1, o2, o3);
        *(float4*)(dst + j * C_OUT + 4) = make_float4(o4, o5, o6, o7);
    }
}

// ---------------------------------------------------------------------------
// Kernel B (r18): EXACT r10 structure + sync protocol. ONE change: the
// clamped-case log1pf results are hoisted to per-thread init. The operands
// are laundered through an empty asm so the compiler CANNOT constant-fold
// them (host-libm folding could 1-ulp-mismatch the device call); the hoisted
// calls are the SAME device log1pf on the SAME values (-0.01f / -0.99f)
// the old in-loop code passed post-clamp => bit-identical ls trajectory.
// In-loop, clamped pixels (the vast majority: alpha<=0.01 once dist is
// moderate) now run dist -> t -> v_exp -> compare -> add-const (~60cy chain)
// instead of the full ~40-60-inst libm log1pf chain (~200cy). Mid-range
// pixels keep the exact in-loop log1pf(-alpha). This attacks the measured
// 29%-issue-efficiency latency floor (8 dependent chains per lane-slot is a
// problem-size constant; only chain LENGTH is variable).
// ---------------------------------------------------------------------------
#define NT 1024
#define CHUNK (HW / BLK_PER_B)   // 2048

__global__ __launch_bounds__(NT) void stick_kernel(
    const float* __restrict__ feat,        // [B][HW][C_OUT]
    const float* __restrict__ rand_pixel,  // [B][HW]
    const float* __restrict__ log_sigma_p, // scalar
    float* __restrict__ masks,             // [B][K][HW]
    float* __restrict__ scopes,            // [B][K][HW]
    unsigned long long* __restrict__ flags,// [7][B][BLK_PER_B]
    const unsigned long long* __restrict__ seed0) // [B][16]
{
    // batch b's 8 blocks share blockIdx%8 -> same XCD (L2-local flags).
    const int b    = blockIdx.x & 31;
    const int blk  = blockIdx.x >> 5;
    const int tid  = threadIdx.x;
    const int lane = tid & 63;
    const int wid  = tid >> 6;             // 0..15

    const float inv_sigma = expf(-(*log_sigma_p));

    // hoisted clamped-case log1pf values — laundered so they are computed by
    // the DEVICE libm at runtime (bit-identical to the old in-loop calls).
    float c01 = -0.01f, c99 = -0.99f;
    asm volatile("" : "+v"(c01), "+v"(c99));
    const float DLS_LO = log1pf(c01);      // ls-delta when alpha clamps to 0.01
    const float DLS_HI = log1pf(c99);      // ls-delta when alpha clamps to 0.99

    const float* fb = feat + (size_t)b * HW * C_OUT;
    const float* rb = rand_pixel + (size_t)b * HW;
    float* mb = masks  + (size_t)b * (K_STEPS * HW);
    float* sb = scopes + (size_t)b * (K_STEPS * HW);

    const int p0 = blk * CHUNK + 2 * tid;  // adjacent pixels p0, p0+1

    const float4 f0a = *(const float4*)(fb + (size_t)p0 * C_OUT);
    const float4 f0b = *(const float4*)(fb + (size_t)p0 * C_OUT + 4);
    const float4 f1a = *(const float4*)(fb + (size_t)p0 * C_OUT + 8);
    const float4 f1b = *(const float4*)(fb + (size_t)p0 * C_OUT + 12);

    const float2 rr = *(const float2*)(rb + p0);
    float ls0 = 0.0f, ls1 = 0.0f;
    nt_store2(sb + p0, 0.0f, 0.0f);        // log_scopes[:,0] = 0

    __shared__ float swv[2][16];
    __shared__ int   swi[2][16];
    __shared__ int   sSeed[2];

    for (int s = 0; s < NROUNDS; ++s) {
        const int par = s & 1;
        int seedIdx;

        if (s == 0) {
            // seed precomputed by semiconv: reduce 16 slots, no sync
            float gv = -1.0f; int gi = 0x7fffffff;
            if (lane < 16) {
                const unsigned long long got = seed0[(b << 4) | lane];
                gv = __uint_as_float((unsigned int)(got >> 32));
                gi = (int)(unsigned int)(got & 0xffffffffULL);
            }
            #pragma unroll
            for (int off = 1; off < 16; off <<= 1) {
                const float ov = __shfl_xor(gv, off);
                const int   oi = __shfl_xor(gi, off);
                if (ov > gv || (ov == gv && oi < gi)) { gv = ov; gi = oi; }
            }
            seedIdx = __shfl(gi, 0);
        } else {
            const int recbase = (s * BATCH + b) * BLK_PER_B;

            // ---- per-thread argmax of rand * exp(log_scope) ----
            float bv; int bi;
            {
                const float v0 = rr.x * expf(ls0);
                const float v1 = rr.y * expf(ls1);
                bv = v0; bi = p0;
                if (v1 > bv) { bv = v1; bi = p0 + 1; }  // strict > keeps lower idx
            }
            #pragma unroll
            for (int off = 1; off < 64; off <<= 1) {
                const float ov = __shfl_xor(bv, off);
                const int   oi = __shfl_xor(bi, off);
                if (ov > bv || (ov == bv && oi < bi)) { bv = ov; bi = oi; }
            }
            if (lane == 0) { swv[par][wid] = bv; swi[par][wid] = bi; }
            __syncthreads();               // barrier 1

            // ---- wave 0: reduce, publish, poll peers, global reduce ----
            if (wid == 0) {
                float v = (lane < 16) ? swv[par][lane] : -1.0f;
                int   ix = (lane < 16) ? swi[par][lane] : 0x7fffffff;
                #pragma unroll
                for (int off = 1; off < 16; off <<= 1) {
                    const float ov = __shfl_xor(v, off);
                    const int   oi = __shfl_xor(ix, off);
                    if (ov > v || (ov == v && oi < ix)) { v = ov; ix = oi; }
                }
                if (lane == 0) {
                    const unsigned long long pk =
                        ((unsigned long long)__float_as_uint(v) << 32) |
                        (unsigned long long)(unsigned int)(ix + 1);
                    __hip_atomic_store(&flags[recbase + blk], pk,
                                       __ATOMIC_RELAXED, __HIP_MEMORY_SCOPE_AGENT);
                }
                float gv = -1.0f; int gi = 0x7fffffff;
                if (lane < BLK_PER_B) {
                    unsigned long long got;
                    do {
                        got = __hip_atomic_load(&flags[recbase + lane],
                                                __ATOMIC_RELAXED,
                                                __HIP_MEMORY_SCOPE_AGENT);
                    } while (got == 0ULL);
                    gv = __uint_as_float((unsigned int)(got >> 32));
                    gi = (int)(unsigned int)(got & 0xffffffffULL) - 1;
                }
                #pragma unroll
                for (int off = 1; off < 8; off <<= 1) {
                    const float ov = __shfl_xor(gv, off);
                    const int   oi = __shfl_xor(gi, off);
                    if (ov > gv || (ov == gv && oi < gi)) { gv = ov; gi = oi; }
                }
                if (lane == 0) sSeed[par] = gi;
            }
            __syncthreads();               // barrier 2
            seedIdx = sSeed[par];
        }

        // seed features (uniform address -> broadcast load, L2/L3-hot)
        const float4 s0 = *(const float4*)(fb + (size_t)seedIdx * C_OUT);
        const float4 s1 = *(const float4*)(fb + (size_t)seedIdx * C_OUT + 4);

        // ---- distances, alpha, mask/scope update ----
        float sq0 = 0.0f, sq1 = 0.0f, d;
        d = f0a.x - s0.x; sq0 += d * d;
        d = f0a.y - s0.y; sq0 += d * d;
        d = f0a.z - s0.z; sq0 += d * d;
        d = f0a.w - s0.w; sq0 += d * d;
        d = f0b.x - s1.x; sq0 += d * d;
        d = f0b.y - s1.y; sq0 += d * d;
        d = f0b.z - s1.z; sq0 += d * d;
        d = f0b.w - s1.w; sq0 += d * d;
        d = f1a.x - s0.x; sq1 += d * d;
        d = f1a.y - s0.y; sq1 += d * d;
        d = f1a.z - s0.z; sq1 += d * d;
        d = f1a.w - s0.w; sq1 += d * d;
        d = f1b.x - s1.x; sq1 += d * d;
        d = f1b.y - s1.y; sq1 += d * d;
        d = f1b.z - s1.z; sq1 += d * d;
        d = f1b.w - s1.w; sq1 += d * d;

        float m0, m1;
        {
            const float t = sq0 * inv_sigma;
            const float alpha = expf(-t);
            float log_a, dls;
            if (alpha >= 0.99f)      { log_a = -0.010050336f; dls = DLS_HI; } // ln(0.99), log1p(-0.99)
            else if (alpha <= 0.01f) { log_a = -4.6051702f;   dls = DLS_LO; } // ln(0.01), log1p(-0.01)
            else                     { log_a = -t; dls = log1pf(-alpha); }
            m0 = ls0 + log_a;
            ls0 += dls;
        }
        {
            const float t = sq1 * inv_sigma;
            const float alpha = expf(-t);
            float log_a, dls;
            if (alpha >= 0.99f)      { log_a = -0.010050336f; dls = DLS_HI; }
            else if (alpha <= 0.01f) { log_a = -4.6051702f;   dls = DLS_LO; }
            else                     { log_a = -t; dls = log1pf(-alpha); }
            m1 = ls1 + log_a;
            ls1 += dls;
        }
        nt_store2(mb + s * HW + p0, m0, m1);
        nt_store2(sb + (s + 1) * HW + p0, ls0, ls1);
    }

    nt_store2(mb + (K_STEPS - 1) * HW + p0, ls0, ls1);  // last mask = final scope
}

extern "C" void kernel_launch(void* const* d_in, const int* in_sizes, int n_in,
                              void* d_out, int out_size, void* d_ws, size_t ws_size,
                              hipStream_t stream) {
    const float* x          = (const float*)d_in[0];  // [32,64,128,128]
    const float* rand_pixel = (const float*)d_in[1];  // [32,1,128,128]
    const float* conv_w     = (const float*)d_in[2];  // [8,64]
    const float* conv_b     = (const float*)d_in[3];  // [8]
    const float* gate       = (const float*)d_in[4];  // scalar
    const float* log_sigma  = (const float*)d_in[5];  // scalar

    float* masks  = (float*)d_out;                          // [32,8,128,128]
    float* scopes = masks + (long long)BATCH * K_STEPS * HW;

    float* feat = (float*)d_ws;  // 16.8 MB
    unsigned long long* flags =
        (unsigned long long*)((char*)d_ws + FEAT_BYTES);               // 14 KB
    unsigned long long* seed0 = flags + NFLAGS;                        // 4 KB

    semiconv_kernel<<<(BATCH * HW) / (256 * 4), 256, 0, stream>>>(
        x, conv_w, conv_b, gate, rand_pixel, feat, flags, seed0);

    stick_kernel<<<BATCH * BLK_PER_B, NT, 0, stream>>>(
        feat, rand_pixel, log_sigma, masks, scopes, flags, seed0);
}